// Round 3
// baseline (160.718 us; speedup 1.0000x reference)
//
#include <hip/hip_runtime.h>
#include <hip/hip_bf16.h>

#define B_    4
#define C_    64
#define H_    192
#define W_    192
#define TAPS_ 9
#define MID_  12
#define HW_   (H_ * W_)
#define K_TOT 576                      // C_ * TAPS_
#define AT_STRIDE 72                   // bf16 elems per a_T row (8 chunks data + 1 pad chunk)
#define ATROWS 104                     // half-row a_T: 96 outputs + 8 halo
#define WBLK  96                       // output pixels per block

constexpr float STD_ = 0.47140452079103173f;  // sqrt(2)/3

using bf16 = __hip_bfloat16;
typedef __attribute__((ext_vector_type(4))) float  f32x4;
typedef __attribute__((ext_vector_type(8))) short  short8;

__device__ __forceinline__ unsigned short f2bf_bits(float v) {
    union { bf16 h; unsigned short u; } cv;
    cv.h = __float2bfloat16(v);   // RNE
    return cv.u;
}

// aT XOR swizzle: 16-B chunks within a row permuted by key=(row>>2)&7.
// Word-granular address (cw = word col 0..31; data only, pad chunk 8 untouched).
__device__ __forceinline__ int at_word(int row, int cw) {
    int key = (row >> 2) & 7;
    return row * (AT_STRIDE / 2) + ((((cw >> 2) ^ key) & 7) << 2) + (cw & 3);
}

// ---------------------------------------------------------------------------
// k_pre: fused {w2 repack -> bf16 [o][t*64+c]} (blocks 0..143) and
//        {x row partial sums} (blocks 144..911).
// ---------------------------------------------------------------------------
__global__ __launch_bounds__(256) void k_pre(const float* __restrict__ x,
                                             const float* __restrict__ w2,
                                             unsigned short* __restrict__ w2bf,
                                             float* __restrict__ partials) {
    int bx = blockIdx.x;
    if (bx < 144) {
        int d = bx * 256 + threadIdx.x;          // dest index, 36864 total
        int o = d / K_TOT;
        int rem = d - o * K_TOT;
        int t = rem >> 6;
        int c = rem & 63;
        w2bf[d] = f2bf_bits(w2[(o * C_ + c) * TAPS_ + t]);
        return;
    }
    bx -= 144;
    int bc = bx / 3, part = bx - 3 * (bx / 3);
    const float4* p = (const float4*)(x + (size_t)bc * HW_ + part * 12288);
    float s = 0.f;
    #pragma unroll
    for (int k = 0; k < 12; ++k) {
        float4 u = p[threadIdx.x + k * 256];
        s += u.x + u.y + u.z + u.w;
    }
    #pragma unroll
    for (int off = 32; off; off >>= 1) s += __shfl_down(s, off);
    __shared__ float red[4];
    if ((threadIdx.x & 63) == 0) red[threadIdx.x >> 6] = s;
    __syncthreads();
    if (threadIdx.x == 0)
        partials[bx] = red[0] + red[1] + red[2] + red[3];
}

// ---------------------------------------------------------------------------
// k_cf: reduce partials -> g; channel branch; FilterNorm -> cfn (B,C,9) f32.
// ---------------------------------------------------------------------------
__global__ __launch_bounds__(256) void k_cf(const float* __restrict__ partials,
                                            const float* __restrict__ cw1,
                                            const float* __restrict__ cb1,
                                            const float* __restrict__ cw2,
                                            const float* __restrict__ cb2,
                                            float* __restrict__ cfn) {
    __shared__ float g_l[B_ * C_];
    __shared__ float h1_l[B_ * MID_];
    int tid = threadIdx.x;
    g_l[tid] = (partials[tid * 3] + partials[tid * 3 + 1] + partials[tid * 3 + 2])
               * (1.0f / HW_);
    __syncthreads();
    if (tid < B_ * MID_) {
        int b = tid / MID_, m = tid % MID_;
        float acc = cb1[m];
        for (int c = 0; c < C_; ++c) acc += g_l[b * C_ + c] * cw1[m * C_ + c];
        h1_l[tid] = fmaxf(acc, 0.f);
    }
    __syncthreads();
    int b = tid >> 6, c = tid & 63;
    float f[TAPS_];
    float mean = 0.f;
    #pragma unroll
    for (int t = 0; t < TAPS_; ++t) {
        int n = c * TAPS_ + t;
        float acc = cb2[n];
        #pragma unroll
        for (int m = 0; m < MID_; ++m) acc += h1_l[b * MID_ + m] * cw2[n * MID_ + m];
        f[t] = acc;
        mean += acc;
    }
    mean *= (1.f / TAPS_);
    float var = 0.f;
    #pragma unroll
    for (int t = 0; t < TAPS_; ++t) { float d = f[t] - mean; var += d * d; }
    var *= (1.f / (TAPS_ - 1));
    float scale = STD_ / (sqrtf(fmaxf(var, 0.f)) + 1e-10f);
    #pragma unroll
    for (int t = 0; t < TAPS_; ++t)
        cfn[(b * C_ + c) * TAPS_ + t] = (f[t] - mean) * scale;
}

// ---------------------------------------------------------------------------
// k_main: one block per (b, h, w-half). grid = 1536 -> 6 blocks/CU (vs 3),
// LDS 19.2 KB/block. Halves of the same row share an XCD (side = bx/768,
// 768 % 8 == 0) for L2 reuse of the x rows.
//   A: spatial filters for the 100 valid pixels -> s_l[u&1][t][u>>1]
//   B: wave<->16ch, lane<->2 px (50 lanes); writes a_T bf16, XOR swizzle
//   C: 1x9 conv as 16x16x32 MFMA GEMM M=64 x N=96 x K=576; wave = 16 o-chans
//      x six 16-wide w-tiles (acc = 6 f32x4); A-frags streamed via rolling
//      3-reg window, dist-2 prefetch.
// ---------------------------------------------------------------------------
__global__ __launch_bounds__(256, 6) void k_main(const float* __restrict__ x,
                                                 const float* __restrict__ sw,
                                                 const float* __restrict__ sb,
                                                 const float* __restrict__ cfn,
                                                 const unsigned short* __restrict__ w2bf,
                                                 const float* __restrict__ bias2,
                                                 float* __restrict__ out) {
    __shared__ __align__(16) char smem[19232];
    short*          aT   = (short*)smem;           // 104*72*2 = 14976 B
    unsigned*       aT32 = (unsigned*)smem;
    float*          sw_l = (float*)smem;           // alias (phase A only), 2304 B
    float*          s_l  = (float*)(smem + 14976); // 2*9*52*4 = 3744 B
    float*          b2_l = (float*)(smem + 18720); // 256 B
    float*          sb_l = (float*)(smem + 18976); // 40 B

    int bx = blockIdx.x;
    int side = (bx >= B_ * H_) ? 1 : 0;            // same XCD for both halves
    int bh = bx - side * (B_ * H_);
    int bb = bh / H_;
    int h  = bh - bb * H_;
    int wstart = side * WBLK;                      // first output pixel
    int wv0    = side ? (WBLK - 4) : 0;            // first valid DDF pixel w'
    int roff   = side ? 0 : 4;                     // aT row of first valid px

    int tid = threadIdx.x;
    int lane = tid & 63, wid = tid >> 6;
    int quad = lane >> 4, l16 = lane & 15;
    int obase = wid * 16;

    // ---- stage small tables ----
    for (int i = tid; i < TAPS_ * C_; i += 256) sw_l[i] = sw[i];
    if (tid < C_) b2_l[tid] = bias2[tid];
    if (tid < TAPS_) sb_l[tid] = sb[tid];
    __syncthreads();

    // ---- preload first 2 A-fragments (8 VGPRs, in flight across A+B) ----
    const short* w2s = (const short*)w2bf;
    const short* arow = w2s + (obase + l16) * K_TOT + quad * 8;
    short8 a0 = *(const short8*)(arow);
    short8 a1 = *(const short8*)(arow + 32);

    // ---- Phase A: spatial filters for the 100 valid pixels ----
    if (tid < 100) {
        int w = wv0 + tid;
        float acc[TAPS_];
        #pragma unroll
        for (int t = 0; t < TAPS_; ++t) acc[t] = sb_l[t];
        const float* px = x + (size_t)bb * C_ * HW_ + h * W_ + w;
        #pragma unroll 8
        for (int c = 0; c < C_; ++c) {
            float xv = px[(size_t)c * HW_];
            #pragma unroll
            for (int t = 0; t < TAPS_; ++t) acc[t] = fmaf(xv, sw_l[t * C_ + c], acc[t]);
        }
        float mean = 0.f;
        #pragma unroll
        for (int t = 0; t < TAPS_; ++t) mean += acc[t];
        mean *= (1.f / TAPS_);
        float var = 0.f;
        #pragma unroll
        for (int t = 0; t < TAPS_; ++t) { float d = acc[t] - mean; var += d * d; }
        var *= (1.f / (TAPS_ - 1));
        float scale = STD_ / (sqrtf(fmaxf(var, 0.f)) + 1e-10f);
        float* sp = s_l + (tid & 1) * 468 + (tid >> 1);
        #pragma unroll
        for (int t = 0; t < TAPS_; ++t) sp[t * 52] = (acc[t] - mean) * scale;
    }
    __syncthreads();   // phase B overwrites sw_l alias (aT) and reads s_l

    // ---- zero the 4 a_T halo rows (w' outside the image); swizzle is a
    //      row-local permutation, so linear zeroing covers the same words ----
    if (tid < 4 * (AT_STRIDE / 2)) {
        int rowIdx = tid / (AT_STRIDE / 2);
        int col    = tid - rowIdx * (AT_STRIDE / 2);
        int r = (side ? 100 : 0) + rowIdx;
        aT32[r * (AT_STRIDE / 2) + col] = 0u;
    }

    // ---- Phase B: DDF apply + leaky -> a_T bf16 (swizzled), 2 px/lane ----
    {
        int wbase_c = wid * 16;        // 16 channels per wave
        if (lane < 50) {
            int u0 = 2 * lane;         // local valid-pixel index (pair u0,u0+1)
            int wp = wv0 + u0;         // image pixel of first px (even)
            float sreg0[TAPS_], sreg1[TAPS_];
            {
                const float* sp0 = s_l + lane;        // conflict-free: <=2-way
                const float* sp1 = s_l + 468 + lane;
                #pragma unroll
                for (int t = 0; t < TAPS_; ++t) { sreg0[t] = sp0[t * 52]; sreg1[t] = sp1[t * 52]; }
            }
            bool lm = (side == 0) && (lane == 0);    // w'-1 < 0
            bool pm = (side == 1) && (lane == 49);   // w'+2 > 191
            int rok0 = (h > 0), rok2 = (h < H_ - 1);
            const float* xbase = x + (long)bb * C_ * HW_ + (long)(h - 1) * W_ + wp;
            int rb0 = u0 + roff;
            #pragma unroll 1
            for (int i = 0; i < 16; i += 2) {
                int c0 = wbase_c + i;
                int cu = __builtin_amdgcn_readfirstlane(c0);
                const float* cfp = cfn + bb * (C_ * TAPS_) + cu * TAPS_;
                const float* pc0 = xbase + (long)c0 * HW_;
                const float* pc1 = pc0 + HW_;
                float a00 = 0.f, a01 = 0.f, a10 = 0.f, a11 = 0.f;
                #pragma unroll
                for (int r = 0; r < 3; ++r) {
                    if (r == 0 && !rok0) continue;   // block-uniform branches
                    if (r == 2 && !rok2) continue;
                    const float* p0 = pc0 + r * W_;
                    const float* p1 = pc1 + r * W_;
                    float2 f0 = *(const float2*)p0;  // 8B aligned (wp even)
                    float2 f1 = *(const float2*)p1;
                    float m0 = lm ? 0.f : p0[-1];
                    float m1 = lm ? 0.f : p1[-1];
                    float q0 = pm ? 0.f : p0[2];
                    float q1 = pm ? 0.f : p1[2];
                    float va[4] = { m0, f0.x, f0.y, q0 };
                    float vb[4] = { m1, f1.x, f1.y, q1 };
                    #pragma unroll
                    for (int dc = 0; dc < 3; ++dc) {
                        int t = r * 3 + dc;
                        float cva = cfp[t];
                        float cvb = cfp[TAPS_ + t];
                        a00 = fmaf(va[dc]     * sreg0[t], cva, a00);
                        a01 = fmaf(va[dc + 1] * sreg1[t], cva, a01);
                        a10 = fmaf(vb[dc]     * sreg0[t], cvb, a10);
                        a11 = fmaf(vb[dc + 1] * sreg1[t], cvb, a11);
                    }
                }
                a00 = (a00 >= 0.f) ? a00 : 0.1f * a00;
                a01 = (a01 >= 0.f) ? a01 : 0.1f * a01;
                a10 = (a10 >= 0.f) ? a10 : 0.1f * a10;
                a11 = (a11 >= 0.f) ? a11 : 0.1f * a11;
                int cw = c0 >> 1;                    // word col 0..31
                unsigned pk0 = (unsigned)f2bf_bits(a00) | ((unsigned)f2bf_bits(a10) << 16);
                unsigned pk1 = (unsigned)f2bf_bits(a01) | ((unsigned)f2bf_bits(a11) << 16);
                aT32[at_word(rb0,     cw)] = pk0;
                aT32[at_word(rb0 + 1, cw)] = pk1;
            }
        }
    }
    __syncthreads();

    // ---- Phase C: MFMA GEMM out[o][w] += A[o][q] * B[q][w], q = t*64 + c ----
    {
        f32x4 acc[6];
        #pragma unroll
        for (int n = 0; n < 6; ++n) acc[n] = (f32x4){0.f, 0.f, 0.f, 0.f};

        #pragma unroll 1
        for (int kk = 0; kk < 18; ++kk) {
            short8 a2 = a1;
            if (kk < 16) a2 = *(const short8*)(arow + (kk + 2) * 32);  // dist-2 stream
            int t = kk >> 1;
            int ch = ((kk & 1) << 2) + quad;     // 16-B chunk index 0..7
            int rowb = l16 + t;
            int key0 = (rowb >> 2) & 7;          // key(n) = key0 ^ (4*(n&1))
            int off0 = rowb * AT_STRIDE + (((ch ^ key0) & 7) << 3);
            int off1 = rowb * AT_STRIDE + (((ch ^ key0 ^ 4) & 7) << 3);
            #pragma unroll
            for (int n = 0; n < 6; ++n) {
                int off = ((n & 1) ? off1 : off0) + n * 16 * AT_STRIDE;
                short8 bf = *(const short8*)(aT + off);
                acc[n] = __builtin_amdgcn_mfma_f32_16x16x32_bf16(a0, bf, acc[n], 0, 0, 0);
            }
            a0 = a1; a1 = a2;
        }

        // epilogue: bias + residual add, C/D layout col=lane&15, row=quad*4+reg
        size_t xbase = (size_t)bb * C_ * HW_ + (size_t)h * W_;
        #pragma unroll
        for (int n = 0; n < 6; ++n) {
            int w = wstart + n * 16 + l16;
            #pragma unroll
            for (int reg = 0; reg < 4; ++reg) {
                int o = obase + quad * 4 + reg;
                size_t idx = xbase + (size_t)o * HW_ + w;
                out[idx] = acc[n][reg] + b2_l[o] + x[idx];
            }
        }
    }
}

// ---------------------------------------------------------------------------
extern "C" void kernel_launch(void* const* d_in, const int* in_sizes, int n_in,
                              void* d_out, int out_size, void* d_ws, size_t ws_size,
                              hipStream_t stream) {
    const float* x   = (const float*)d_in[0];
    const float* sw  = (const float*)d_in[1];
    const float* sb  = (const float*)d_in[2];
    const float* cw1 = (const float*)d_in[3];
    const float* cb1 = (const float*)d_in[4];
    const float* cw2 = (const float*)d_in[5];
    const float* cb2 = (const float*)d_in[6];
    const float* w2  = (const float*)d_in[7];
    const float* b2  = (const float*)d_in[8];
    float* out = (float*)d_out;

    unsigned short* w2bf = (unsigned short*)d_ws;                 // 73728 B
    float* partials = (float*)((char*)d_ws + 73728);              // 3072 B
    float* cfn      = (float*)((char*)d_ws + 76800);              // 9216 B

    hipLaunchKernelGGL(k_pre, dim3(912), dim3(256), 0, stream, x, w2, w2bf, partials);
    hipLaunchKernelGGL(k_cf, dim3(1), dim3(256), 0, stream,
                       partials, cw1, cb1, cw2, cb2, cfn);
    hipLaunchKernelGGL(k_main, dim3(B_ * H_ * 2), dim3(256), 0, stream,
                       x, sw, sb, cfn, w2bf, b2, out);
}